// Round 1
// baseline (3670.128 us; speedup 1.0000x reference)
//
#include <hip/hip_runtime.h>

typedef __attribute__((ext_vector_type(8))) short short8;
typedef __attribute__((ext_vector_type(4))) float f32x4;
typedef __attribute__((ext_vector_type(4))) unsigned short ushort4v;

#define R_DIM 1024
#define KE    1056      // 1024 state + 8 x + 24 zero pad
#define T_LEN 65536
#define CCH   1024      // chunks
#define LCH   64        // real steps per chunk
#define WARM  64        // warmup steps
#define STEPS 128       // WARM + LCH
#define RBN   32        // row-block WGs per column group
#define WGR   32        // rows per WG
#define CGN   16        // column groups
#define WGC   64        // columns per WG

static __device__ __forceinline__ unsigned short f2bf(float f){
  unsigned u = __builtin_bit_cast(unsigned, f);
  u += 0x7fffu + ((u >> 16) & 1u);
  return (unsigned short)(u >> 16);
}
static __device__ __forceinline__ float fast_tanh(float x){
  float e = __expf(2.0f * x);          // inf/0 saturate correctly to +/-1
  return 1.0f - 2.0f / (e + 1.0f);
}

// ---- prep: W_ext = [W_res | W_in | 0] in bf16, row-major [1024][1056] ----
__global__ void k_build_wext(const float* __restrict__ Wres,
                             const float* __restrict__ Win,
                             short* __restrict__ Wext){
  int idx = blockIdx.x * 256 + threadIdx.x;       // 1024*1056 = 4224*256
  int r = idx / KE, k = idx % KE;
  float v = 0.0f;
  if (k < 1024)      v = Wres[(size_t)r * 1024 + k];
  else if (k < 1032) v = Win[r * 8 + (k - 1024)];
  Wext[idx] = (short)f2bf(v);
}

// ---- prep: zero S0+S1 (contiguous) ----
__global__ void k_zero(unsigned* __restrict__ p){
  p[blockIdx.x * 256 + threadIdx.x] = 0u;
}

// ---- prep: x-slot of S0 for iteration 0, zero counters ----
__global__ void k_init_x(const float* __restrict__ in, short* __restrict__ S0,
                         unsigned* __restrict__ cnt){
  int c = blockIdx.x * 256 + threadIdx.x;
  if (blockIdx.x == 0 && threadIdx.x < CGN) cnt[threadIdx.x * 32] = 0u;
  if (c < CCH){
    int t0 = c * LCH - WARM;
    ushort4v xa = {0,0,0,0}, xb = {0,0,0,0};
    if (t0 >= 0){
      const float* xp = in + (size_t)t0 * 8;
      xa = ushort4v{ f2bf(xp[0]), f2bf(xp[1]), f2bf(xp[2]), f2bf(xp[3]) };
      xb = ushort4v{ f2bf(xp[4]), f2bf(xp[5]), f2bf(xp[6]), f2bf(xp[7]) };
    }
    *(ushort4v*)(S0 + (size_t)c * KE + 1024) = xa;
    *(ushort4v*)(S0 + (size_t)c * KE + 1028) = xb;
  }
}

// ---- output rows 1024..1031 = inputs^T (exact fp32 copy) ----
__global__ void k_xrows(const float* __restrict__ in, float* __restrict__ out){
  int t = blockIdx.x * 256 + threadIdx.x;
  const float4 a = *(const float4*)(in + (size_t)t * 8);
  const float4 b = *(const float4*)(in + (size_t)t * 8 + 4);
  out[(size_t)(R_DIM + 0) * T_LEN + t] = a.x;
  out[(size_t)(R_DIM + 1) * T_LEN + t] = a.y;
  out[(size_t)(R_DIM + 2) * T_LEN + t] = a.z;
  out[(size_t)(R_DIM + 3) * T_LEN + t] = a.w;
  out[(size_t)(R_DIM + 4) * T_LEN + t] = b.x;
  out[(size_t)(R_DIM + 5) * T_LEN + t] = b.y;
  out[(size_t)(R_DIM + 6) * T_LEN + t] = b.z;
  out[(size_t)(R_DIM + 7) * T_LEN + t] = b.w;
}

// ---- hist[t][r] (bf16) -> out[r][t] (f32), tiled transpose ----
__global__ void k_transpose(const short* __restrict__ hist, float* __restrict__ out){
  __shared__ float tile[64][65];
  const int t0 = blockIdx.x * 64;
  const int r0 = blockIdx.y * 64;
  for (int it = 0; it < 2; ++it){
    int id = it * 256 + threadIdx.x;     // 512 chunks of 8 bf16
    int tr = id >> 3;
    int c8 = (id & 7) * 8;
    short8 v = *(const short8*)(hist + (size_t)(t0 + tr) * KE + r0 + c8);
    #pragma unroll
    for (int j = 0; j < 8; ++j){
      unsigned u = ((unsigned)(unsigned short)v[j]) << 16;
      tile[tr][c8 + j] = __builtin_bit_cast(float, u);
    }
  }
  __syncthreads();
  #pragma unroll
  for (int p = 0; p < 16; ++p){
    int rr = (threadIdx.x >> 6) + p * 4;
    int tc = threadIdx.x & 63;
    out[(size_t)(r0 + rr) * T_LEN + t0 + tc] = tile[tc][rr];
  }
}

// ---- main persistent-ish stepped kernel ----
template<bool HIST>
__global__ __launch_bounds__(256, 2)
void k_esn(const float* __restrict__ inputs, const short* __restrict__ Wext,
           short* __restrict__ S0, short* __restrict__ S1,
           short* __restrict__ hist, unsigned* __restrict__ cnt,
           float* __restrict__ out)
{
  __shared__ __align__(16) char lds[65536];   // 32 rows x 2048B, XOR-swizzled
  const int tid  = threadIdx.x;
  const int cg   = blockIdx.x & (CGN - 1);
  const int rb   = blockIdx.x / CGN;
  const int lane = tid & 63;
  const int wave = tid >> 6;
  const int l15  = lane & 15, l4 = lane >> 4;
  const int growbase = rb * WGR;
  const int cglob = cg * WGC + wave * 16 + l15;

  // stage W rows [growbase, +32), k<1024 into LDS (16B-unit XOR swizzle)
  {
    const char* src = (const char*)Wext + (size_t)growbase * (KE * 2);
    #pragma unroll
    for (int it = 0; it < 16; ++it){
      int chunk = it * 256 + tid;          // 4096 chunks of 16B
      int row = chunk >> 7;                // 128 chunks per row (2048B)
      int kb  = (chunk & 127) << 4;
      uint4 v = *(const uint4*)(src + (size_t)row * (KE * 2) + kb);
      *(uint4*)(&lds[row * 2048 + (kb ^ ((row & 7) << 4))]) = v;
    }
  }
  __syncthreads();

  unsigned* mycnt = cnt + cg * 32;
  const int abase = l15 * 2048;            // A row l15 (and +16 via offset 32768)
  const int sw    = (l15 & 7) << 4;
  const int kl4   = l4 * 16;               // byte offset within k-group

  for (int k = 0; k < STEPS; ++k){
    if (k > 0){
      if (tid == 0){
        unsigned target = (unsigned)(RBN * k);
        int guard = 0;
        while (__hip_atomic_load(mycnt, __ATOMIC_RELAXED, __HIP_MEMORY_SCOPE_AGENT) < target){
          __builtin_amdgcn_s_sleep(2);
          if (++guard > 10000000) break;   // failsafe: no hang on bug
        }
        __builtin_amdgcn_fence(__ATOMIC_ACQUIRE, "agent");
      }
      __syncthreads();
    }

    // B source row (this lane's column): [s_t ; x_t ; 0]
    const short* brow;
    if (!HIST || k <= WARM){
      const short* Sp = (k & 1) ? S1 : S0;
      brow = Sp + (size_t)cglob * KE;
    } else {
      brow = hist + (size_t)(cglob * LCH + (k - WARM) - 1) * KE;
    }
    const short* bptr = brow + l4 * 8;

    f32x4 z0 = {0.f,0.f,0.f,0.f}, z1 = {0.f,0.f,0.f,0.f};
    short8 b = *(const short8*)bptr;
    #pragma unroll
    for (int kk = 0; kk < 32; ++kk){
      short8 bn = *(const short8*)(bptr + (kk + 1) * 32);  // prefetch (kk=31 -> K-ext block)
      int off = abase + (((kk * 64) + kl4) ^ sw);
      short8 a0 = *(const short8*)(&lds[off]);
      short8 a1 = *(const short8*)(&lds[off + 32768]);     // row +16, same swizzle
      z0 = __builtin_amdgcn_mfma_f32_16x16x32_bf16(a0, b, z0, 0, 0, 0);
      z1 = __builtin_amdgcn_mfma_f32_16x16x32_bf16(a1, b, z1, 0, 0, 0);
      b = bn;
    }
    { // K-ext tail (k in [1024,1056)): A from global W_ext
      const short* ag = Wext + (size_t)(growbase + l15) * KE + 1024 + l4 * 8;
      short8 a0 = *(const short8*)ag;
      short8 a1 = *(const short8*)(ag + (size_t)16 * KE);
      z0 = __builtin_amdgcn_mfma_f32_16x16x32_bf16(a0, b, z0, 0, 0, 0);
      z1 = __builtin_amdgcn_mfma_f32_16x16x32_bf16(a1, b, z1, 0, 0, 0);
    }

    // epilogue: s = tanh(z); write next-state row
    const int tk = cglob * LCH + k - WARM;   // t(k) for this column (valid k>=WARM)
    short* wrow;
    if (!HIST || k + 1 <= WARM){
      short* Sn = (k & 1) ? S0 : S1;
      wrow = Sn + (size_t)cglob * KE;
    } else {
      wrow = hist + (size_t)tk * KE;
    }
    #pragma unroll
    for (int mi = 0; mi < 2; ++mi){
      f32x4 z = mi ? z1 : z0;
      float s0 = fast_tanh(z[0]), s1 = fast_tanh(z[1]);
      float s2 = fast_tanh(z[2]), s3 = fast_tanh(z[3]);
      ushort4v pk = ushort4v{ f2bf(s0), f2bf(s1), f2bf(s2), f2bf(s3) };
      *(ushort4v*)(wrow + growbase + mi * 16 + l4 * 4) = pk;
      if (!HIST && k >= WARM){
        float* op = out + (size_t)(growbase + mi * 16 + l4 * 4) * T_LEN + tk;
        op[0] = s0; op[(size_t)T_LEN] = s1;
        op[(size_t)2 * T_LEN] = s2; op[(size_t)3 * T_LEN] = s3;
      }
    }

    // x for next iteration (rb 0 only), into same destination row set
    if (rb == 0 && (k + 1) < STEPS && tid < WGC){
      int c = cg * WGC + tid;
      short* xrow;
      if (!HIST || k + 1 <= WARM){
        short* Sn = (k & 1) ? S0 : S1;
        xrow = Sn + (size_t)c * KE;
      } else {
        xrow = hist + (size_t)(c * LCH + k - WARM) * KE;
      }
      int tn = c * LCH + (k + 1) - WARM;
      ushort4v xa = {0,0,0,0}, xb = {0,0,0,0};
      if (tn >= 0){
        const float* xp = inputs + (size_t)tn * 8;
        xa = ushort4v{ f2bf(xp[0]), f2bf(xp[1]), f2bf(xp[2]), f2bf(xp[3]) };
        xb = ushort4v{ f2bf(xp[4]), f2bf(xp[5]), f2bf(xp[6]), f2bf(xp[7]) };
      }
      *(ushort4v*)(xrow + 1024) = xa;
      *(ushort4v*)(xrow + 1028) = xb;
    }

    __syncthreads();
    if (tid == 0 && (k + 1) < STEPS){
      __hip_atomic_fetch_add(mycnt, 1u, __ATOMIC_RELEASE, __HIP_MEMORY_SCOPE_AGENT);
    }
  }
}

extern "C" void kernel_launch(void* const* d_in, const int* in_sizes, int n_in,
                              void* d_out, int out_size, void* d_ws, size_t ws_size,
                              hipStream_t stream)
{
  (void)in_sizes; (void)n_in; (void)out_size;
  const float* inputs = (const float*)d_in[0];
  const float* Win    = (const float*)d_in[1];
  const float* Wres   = (const float*)d_in[2];
  float* out = (float*)d_out;
  char* ws = (char*)d_ws;

  short*    Wext = (short*)(ws);                       // 2,162,688 B
  short*    S0   = (short*)(ws + 2162688);             // 2,162,688 B
  short*    S1   = (short*)(ws + 2162688 * 2);         // 2,162,688 B
  unsigned* cnt  = (unsigned*)(ws + 2162688 * 3);      // 2,048 B
  short*    hist = (short*)(ws + 6490112);             // 65536*1056*2 = 138,412,032 B
  const bool hist_ok = ws_size >= (6490112ull + 138412032ull);

  hipLaunchKernelGGL(k_build_wext, dim3(4224), dim3(256), 0, stream, Wres, Win, Wext);
  hipLaunchKernelGGL(k_zero,       dim3(4224), dim3(256), 0, stream, (unsigned*)S0);
  hipLaunchKernelGGL(k_init_x,     dim3(4),    dim3(256), 0, stream, inputs, S0, cnt);
  hipLaunchKernelGGL(k_xrows,      dim3(256),  dim3(256), 0, stream, inputs, out);
  if (hist_ok){
    hipLaunchKernelGGL((k_esn<true>),  dim3(RBN * CGN), dim3(256), 0, stream,
                       inputs, Wext, S0, S1, hist, cnt, out);
    hipLaunchKernelGGL(k_transpose, dim3(1024, 16), dim3(256), 0, stream, hist, out);
  } else {
    hipLaunchKernelGGL((k_esn<false>), dim3(RBN * CGN), dim3(256), 0, stream,
                       inputs, Wext, S0, S1, hist, cnt, out);
  }
}

// Round 3
// 835.615 us; speedup vs baseline: 4.3921x; 4.3921x over previous
//
#include <hip/hip_runtime.h>
#include <cstdint>

typedef __attribute__((ext_vector_type(8))) short short8;
typedef __attribute__((ext_vector_type(4))) float f32x4;
typedef __attribute__((ext_vector_type(4))) unsigned u32x4;

#define R_DIM 1024
#define KE    1056      // 1024 state + 8 x + 24 zero pad
#define T_LEN 65536
#define LCH   64        // real steps per chunk
#define WARM  32        // warmup steps (lambda^32 << bf16 noise floor)
#define STEPS (WARM + LCH)   // 96
#define CGN   32        // column groups (32 cols each)
#define WGC   32        // cols per WG
#define RWG   8         // row-WGs per group (128 rows each)

static __device__ __forceinline__ unsigned short f2bf(float f){
  unsigned u = __builtin_bit_cast(unsigned, f);
  u += 0x7fffu + ((u >> 16) & 1u);
  return (unsigned short)(u >> 16);
}
static __device__ __forceinline__ float fast_tanh(float x){
  float e = __expf(2.0f * x);          // inf/0 saturate correctly to +/-1
  return 1.0f - 2.0f / (e + 1.0f);
}

// ---- prep: W_ext = [W_res | W_in | 0] in bf16, row-major [1024][1056] ----
// zeros at k>=1032 are LOAD-BEARING: they null garbage in B pad region.
__global__ void k_build_wext(const float* __restrict__ Wres,
                             const float* __restrict__ Win,
                             short* __restrict__ Wext){
  int idx = blockIdx.x * 256 + threadIdx.x;       // 1024*1056 = 4224*256
  int r = idx / KE, k = idx % KE;
  float v = 0.0f;
  if (k < 1024)      v = Wres[(size_t)r * 1024 + k];
  else if (k < 1032) v = Win[r * 8 + (k - 1024)];
  Wext[idx] = (short)f2bf(v);
}

// ---- prep: zero S0+S1 (contiguous 2 x 2,162,688 B) ----
__global__ void k_zero(unsigned* __restrict__ p){
  p[blockIdx.x * 256 + threadIdx.x] = 0u;
}

// ---- prep: x-slot of S0 for step 0, zero counters ----
__global__ void k_init_x(const float* __restrict__ in, short* __restrict__ S0,
                         unsigned* __restrict__ cnt){
  int c = blockIdx.x * 256 + threadIdx.x;
  if (blockIdx.x == 0 && threadIdx.x < CGN) cnt[threadIdx.x * 16] = 0u;
  if (c < 1024){
    int t0 = c * LCH - WARM;
    uint4 xv = {0,0,0,0};
    if (t0 >= 0){
      const float4 A4 = *(const float4*)(in + (size_t)t0 * 8);
      const float4 B4 = *(const float4*)(in + (size_t)t0 * 8 + 4);
      xv.x = f2bf(A4.x) | ((unsigned)f2bf(A4.y) << 16);
      xv.y = f2bf(A4.z) | ((unsigned)f2bf(A4.w) << 16);
      xv.z = f2bf(B4.x) | ((unsigned)f2bf(B4.y) << 16);
      xv.w = f2bf(B4.z) | ((unsigned)f2bf(B4.w) << 16);
    }
    *(uint4*)(S0 + (size_t)c * KE + 1024) = xv;
  }
}

// ---- output rows 1024..1031 = inputs^T (exact fp32 copy) ----
__global__ void k_xrows(const float* __restrict__ in, float* __restrict__ out){
  int t = blockIdx.x * 256 + threadIdx.x;
  const float4 a = *(const float4*)(in + (size_t)t * 8);
  const float4 b = *(const float4*)(in + (size_t)t * 8 + 4);
  out[(size_t)(R_DIM + 0) * T_LEN + t] = a.x;
  out[(size_t)(R_DIM + 1) * T_LEN + t] = a.y;
  out[(size_t)(R_DIM + 2) * T_LEN + t] = a.z;
  out[(size_t)(R_DIM + 3) * T_LEN + t] = a.w;
  out[(size_t)(R_DIM + 4) * T_LEN + t] = b.x;
  out[(size_t)(R_DIM + 5) * T_LEN + t] = b.y;
  out[(size_t)(R_DIM + 6) * T_LEN + t] = b.z;
  out[(size_t)(R_DIM + 7) * T_LEN + t] = b.w;
}

// ---- hist[t][r] (bf16) -> out[r][t] (f32), tiled transpose ----
__global__ void k_transpose(const short* __restrict__ hist, float* __restrict__ out){
  __shared__ float tile[64][65];
  const int t0 = blockIdx.x * 64;
  const int r0 = blockIdx.y * 64;
  for (int it = 0; it < 2; ++it){
    int id = it * 256 + threadIdx.x;     // 512 chunks of 8 bf16
    int tr = id >> 3;
    int c8 = (id & 7) * 8;
    short8 v = *(const short8*)(hist + (size_t)(t0 + tr) * KE + r0 + c8);
    #pragma unroll
    for (int j = 0; j < 8; ++j){
      unsigned u = ((unsigned)(unsigned short)v[j]) << 16;
      tile[tr][c8 + j] = __builtin_bit_cast(float, u);
    }
  }
  __syncthreads();
  #pragma unroll
  for (int p = 0; p < 16; ++p){
    int rr = (threadIdx.x >> 6) + p * 4;
    int tc = threadIdx.x & 63;
    out[(size_t)(r0 + rr) * T_LEN + t0 + tc] = tile[tc][rr];
  }
}

// ---- main stepped kernel: 256 WGs x 512 thr; WG = 128 rows x 32 cols ----
// A (weights) live in VGPRs (136/wave), K split across wave pairs.
// B staged to LDS once per WG per step via sc0/sc1 coherence-point loads.
// __launch_bounds__(512,1): 1 WG/CU, 2 waves/SIMD, <=512 VGPR budget -> no spill.
template<bool HIST>
__global__ __launch_bounds__(512, 1)
void k_esn(const float* __restrict__ inputs, const short* __restrict__ Wext,
           short* __restrict__ S0, short* __restrict__ S1,
           short* __restrict__ hist, unsigned* __restrict__ cnt,
           float* __restrict__ out)
{
  __shared__ __align__(16) char lds[65536];   // 32 cols x 2048B (k<1024), XOR-swizzled
  const int tid  = threadIdx.x;
  const int cg   = blockIdx.x & (CGN - 1);
  const int rwg  = blockIdx.x >> 5;           // group WGs: bid = rwg*32+cg -> same XCD
  const int wv   = tid >> 6;                  // 0..7
  const int lane = tid & 63;
  const int l15  = lane & 15, l4 = lane >> 4;
  const int hi   = wv & 1;                    // K-half of this wave
  const int rbase = rwg * 128 + (wv >> 1) * 32;
  const int colbase = cg * WGC;
  unsigned* mycnt = cnt + cg * 16;

  auto browf = [&](int col, int k) -> const short* {
    if (!HIST || k <= WARM) return ((k & 1) ? S1 : S0) + (size_t)col * KE;
    return hist + (size_t)(col * LCH + (k - WARM) - 1) * KE;
  };
  auto wrowf = [&](int col, int k) -> short* {
    if (!HIST || (k + 1) <= WARM) return ((k & 1) ? S0 : S1) + (size_t)col * KE;
    return hist + (size_t)(col * LCH + (k - WARM)) * KE;
  };

  // ---- loop-invariant A fragments in registers ----
  // hi=0: kk 0..16 (17 frags); hi=1: kk 17..32 (16 frags; kk32 = global-B tail)
  const int NA = hi ? 16 : 17;
  const int KB = hi ? 17 : 0;
  const int NL = hi ? 15 : 17;   // frags consumed from LDS
  short8 a0[17], a1[17];
  {
    const short* abase = Wext + (size_t)(rbase + l15) * KE + l4 * 8;
    #pragma unroll
    for (int i = 0; i < 17; ++i){
      if (i < NA){
        const short* ap = abase + (KB + i) * 32;
        a0[i] = *(const short8*)ap;
        a1[i] = *(const short8*)(ap + (size_t)16 * KE);
      }
    }
  }

  // staging geometry: thread owns col (tid>>4), 8 chunks of 16B spaced 256B
  const int scol = tid >> 4;
  const int skb0 = (tid & 15) << 4;
  const int sswz = (scol & 7) << 4;
  // B-frag read geometry
  const int colb0 = l15 * 2048;
  const int bswz  = (l15 & 7) << 4;
  const int l4b   = l4 * 16;

  for (int k = 0; k < STEPS; ++k){
    if (k > 0){
      if (tid == 0){
        unsigned target = (unsigned)(RWG * k);
        int guard = 0;
        while (__hip_atomic_load(mycnt, __ATOMIC_RELAXED, __HIP_MEMORY_SCOPE_AGENT) < target){
          __builtin_amdgcn_s_sleep(1);
          if (++guard > 5000000) break;      // failsafe: degrade, don't hang
        }
        __builtin_amdgcn_fence(__ATOMIC_ACQUIRE, "agent");
      }
      __syncthreads();                        // A
    }

    // ---- stage B (k<1024) into LDS; sc0/sc1 = read at coherence point ----
    {
      const short* srow = browf(colbase + scol, k);
      const char* sp = (const char*)srow + skb0;
      u32x4 r0,r1,r2,r3,r4,r5,r6,r7;
      asm volatile(
        "global_load_dwordx4 %0, %8, off sc0 sc1\n\t"
        "global_load_dwordx4 %1, %8, off offset:256 sc0 sc1\n\t"
        "global_load_dwordx4 %2, %8, off offset:512 sc0 sc1\n\t"
        "global_load_dwordx4 %3, %8, off offset:768 sc0 sc1\n\t"
        "global_load_dwordx4 %4, %8, off offset:1024 sc0 sc1\n\t"
        "global_load_dwordx4 %5, %8, off offset:1280 sc0 sc1\n\t"
        "global_load_dwordx4 %6, %8, off offset:1536 sc0 sc1\n\t"
        "global_load_dwordx4 %7, %8, off offset:1792 sc0 sc1\n\t"
        "s_waitcnt vmcnt(0)"
        : "=&v"(r0),"=&v"(r1),"=&v"(r2),"=&v"(r3),
          "=&v"(r4),"=&v"(r5),"=&v"(r6),"=&v"(r7)
        : "v"(sp) : "memory");
      char* dst = &lds[scol * 2048];
      *(u32x4*)(dst + ((skb0 +    0) ^ sswz)) = r0;
      *(u32x4*)(dst + ((skb0 +  256) ^ sswz)) = r1;
      *(u32x4*)(dst + ((skb0 +  512) ^ sswz)) = r2;
      *(u32x4*)(dst + ((skb0 +  768) ^ sswz)) = r3;
      *(u32x4*)(dst + ((skb0 + 1024) ^ sswz)) = r4;
      *(u32x4*)(dst + ((skb0 + 1280) ^ sswz)) = r5;
      *(u32x4*)(dst + ((skb0 + 1536) ^ sswz)) = r6;
      *(u32x4*)(dst + ((skb0 + 1792) ^ sswz)) = r7;
    }
    __syncthreads();                          // B

    // ---- K-ext tail B (k 1024..1055) via compiler-tracked coherent loads ----
    unsigned long long t00=0, t01=0, t10=0, t11=0;
    if (hi){
      const unsigned long long* tp0 =
        (const unsigned long long*)(browf(colbase + l15, k) + 1024 + l4 * 8);
      const unsigned long long* tp1 =
        (const unsigned long long*)(browf(colbase + 16 + l15, k) + 1024 + l4 * 8);
      t00 = __hip_atomic_load(tp0,     __ATOMIC_RELAXED, __HIP_MEMORY_SCOPE_AGENT);
      t01 = __hip_atomic_load(tp0 + 1, __ATOMIC_RELAXED, __HIP_MEMORY_SCOPE_AGENT);
      t10 = __hip_atomic_load(tp1,     __ATOMIC_RELAXED, __HIP_MEMORY_SCOPE_AGENT);
      t11 = __hip_atomic_load(tp1 + 1, __ATOMIC_RELAXED, __HIP_MEMORY_SCOPE_AGENT);
    }

    // ---- MFMA K-loop (A from regs, B from LDS) ----
    f32x4 acc00 = {0,0,0,0}, acc01 = {0,0,0,0}, acc10 = {0,0,0,0}, acc11 = {0,0,0,0};
    #pragma unroll
    for (int i = 0; i < 17; ++i){
      if (i < NL){
        int kb = (KB + i) * 64 + l4b;
        const short8 b0 = *(const short8*)(&lds[colb0 + ((kb) ^ bswz)]);
        const short8 b1 = *(const short8*)(&lds[colb0 + 32768 + ((kb) ^ bswz)]);
        acc00 = __builtin_amdgcn_mfma_f32_16x16x32_bf16(a0[i], b0, acc00, 0, 0, 0);
        acc01 = __builtin_amdgcn_mfma_f32_16x16x32_bf16(a0[i], b1, acc01, 0, 0, 0);
        acc10 = __builtin_amdgcn_mfma_f32_16x16x32_bf16(a1[i], b0, acc10, 0, 0, 0);
        acc11 = __builtin_amdgcn_mfma_f32_16x16x32_bf16(a1[i], b1, acc11, 0, 0, 0);
      }
    }
    if (hi){   // kk=32 tail: A index 15, B from registers (pad nulled by Wext zeros)
      u32x4 v0; v0.x=(unsigned)t00; v0.y=(unsigned)(t00>>32); v0.z=(unsigned)t01; v0.w=(unsigned)(t01>>32);
      u32x4 v1; v1.x=(unsigned)t10; v1.y=(unsigned)(t10>>32); v1.z=(unsigned)t11; v1.w=(unsigned)(t11>>32);
      const short8 b0 = __builtin_bit_cast(short8, v0);
      const short8 b1 = __builtin_bit_cast(short8, v1);
      acc00 = __builtin_amdgcn_mfma_f32_16x16x32_bf16(a0[15], b0, acc00, 0, 0, 0);
      acc01 = __builtin_amdgcn_mfma_f32_16x16x32_bf16(a0[15], b1, acc01, 0, 0, 0);
      acc10 = __builtin_amdgcn_mfma_f32_16x16x32_bf16(a1[15], b0, acc10, 0, 0, 0);
      acc11 = __builtin_amdgcn_mfma_f32_16x16x32_bf16(a1[15], b1, acc11, 0, 0, 0);
    }

    // ---- cross-pair K-reduction via LDS (reuse B region after barrier) ----
    __syncthreads();                          // C
    {
      f32x4 wA = hi ? acc00 : acc10;          // this wave's OTHER row-tile partials
      f32x4 wB = hi ? acc01 : acc11;
      char* xp = &lds[wv * 2048 + lane * 32];
      *(f32x4*)(xp)      = wA;
      *(f32x4*)(xp + 16) = wB;
    }
    __syncthreads();                          // D
    {
      const char* pp = &lds[(wv ^ 1) * 2048 + lane * 32];
      f32x4 p0 = *(const f32x4*)(pp);
      f32x4 p1 = *(const f32x4*)(pp + 16);
      f32x4 f0 = (hi ? acc10 : acc00) + p0;   // own row-tile + partner's partial
      f32x4 f1 = (hi ? acc11 : acc01) + p1;
      const int rowb = rbase + hi * 16 + l4 * 4;
      #pragma unroll
      for (int ct = 0; ct < 2; ++ct){
        f32x4 z = ct ? f1 : f0;
        float s0 = fast_tanh(z[0]), s1 = fast_tanh(z[1]);
        float s2 = fast_tanh(z[2]), s3 = fast_tanh(z[3]);
        unsigned long long pk = (unsigned long long)f2bf(s0)
          | ((unsigned long long)f2bf(s1) << 16)
          | ((unsigned long long)f2bf(s2) << 32)
          | ((unsigned long long)f2bf(s3) << 48);
        int col = colbase + ct * 16 + l15;
        short* wp = wrowf(col, k) + rowb;
        asm volatile("global_store_dwordx2 %0, %1, off sc0 sc1"
                     :: "v"(wp), "v"(pk) : "memory");
        if (!HIST && k >= WARM){
          int tk = col * LCH + k - WARM;
          float* op = out + (size_t)rowb * T_LEN + tk;
          op[0] = s0; op[(size_t)T_LEN] = s1;
          op[(size_t)2 * T_LEN] = s2; op[(size_t)3 * T_LEN] = s3;
        }
      }
    }

    // ---- x for next step (one WG per group) ----
    if (rwg == 0 && tid < WGC && (k + 1) < STEPS){
      int col = colbase + tid;
      short* xr = wrowf(col, k) + 1024;
      int tn = col * LCH + (k + 1) - WARM;
      u32x4 xv = {0,0,0,0};
      if (tn >= 0){
        const float4 A4 = *(const float4*)(inputs + (size_t)tn * 8);
        const float4 B4 = *(const float4*)(inputs + (size_t)tn * 8 + 4);
        xv.x = f2bf(A4.x) | ((unsigned)f2bf(A4.y) << 16);
        xv.y = f2bf(A4.z) | ((unsigned)f2bf(A4.w) << 16);
        xv.z = f2bf(B4.x) | ((unsigned)f2bf(B4.y) << 16);
        xv.w = f2bf(B4.z) | ((unsigned)f2bf(B4.w) << 16);
      }
      asm volatile("global_store_dwordx4 %0, %1, off sc0 sc1"
                   :: "v"(xr), "v"(xv) : "memory");
    }

    asm volatile("s_waitcnt vmcnt(0)" ::: "memory");
    __syncthreads();                          // E
    if (tid == 0 && (k + 1) < STEPS)
      __hip_atomic_fetch_add(mycnt, 1u, __ATOMIC_RELEASE, __HIP_MEMORY_SCOPE_AGENT);
  }
}

extern "C" void kernel_launch(void* const* d_in, const int* in_sizes, int n_in,
                              void* d_out, int out_size, void* d_ws, size_t ws_size,
                              hipStream_t stream)
{
  (void)in_sizes; (void)n_in; (void)out_size;
  const float* inputs = (const float*)d_in[0];
  const float* Win    = (const float*)d_in[1];
  const float* Wres   = (const float*)d_in[2];
  float* out = (float*)d_out;
  char* ws = (char*)d_ws;

  short*    Wext = (short*)(ws);                       // 2,162,688 B
  short*    S0   = (short*)(ws + 2162688);             // 2,162,688 B
  short*    S1   = (short*)(ws + 2162688 * 2);         // 2,162,688 B
  unsigned* cnt  = (unsigned*)(ws + 2162688 * 3);      // 32 ctrs x 64B = 2,048 B
  short*    hist = (short*)(ws + 6490112);             // 65536*1056*2 = 138,412,032 B
  const bool hist_ok = ws_size >= (6490112ull + 138412032ull);

  hipLaunchKernelGGL(k_build_wext, dim3(4224), dim3(256), 0, stream, Wres, Win, Wext);
  hipLaunchKernelGGL(k_zero,       dim3(4224), dim3(256), 0, stream, (unsigned*)S0);
  hipLaunchKernelGGL(k_init_x,     dim3(4),    dim3(256), 0, stream, inputs, S0, cnt);
  hipLaunchKernelGGL(k_xrows,      dim3(256),  dim3(256), 0, stream, inputs, out);
  if (hist_ok){
    hipLaunchKernelGGL((k_esn<true>),  dim3(RWG * CGN), dim3(512), 0, stream,
                       inputs, Wext, S0, S1, hist, cnt, out);
    hipLaunchKernelGGL(k_transpose, dim3(1024, 16), dim3(256), 0, stream, hist, out);
  } else {
    hipLaunchKernelGGL((k_esn<false>), dim3(RWG * CGN), dim3(512), 0, stream,
                       inputs, Wext, S0, S1, hist, cnt, out);
  }
}

// Round 4
// 592.672 us; speedup vs baseline: 6.1925x; 1.4099x over previous
//
#include <hip/hip_runtime.h>
#include <cstdint>

typedef __attribute__((ext_vector_type(8))) short short8;
typedef __attribute__((ext_vector_type(4))) float f32x4;
typedef __attribute__((ext_vector_type(4))) unsigned u32x4;

#define R_DIM 1024
#define KE    1056      // 1024 state + 8 x + 24 zero pad
#define T_LEN 65536
#define LCH   64        // real steps per chunk
#define WARM  24        // warmup steps (lambda_eff^24 << bf16 noise floor; 64->32 was noise-identical)
#define STEPS (WARM + LCH)   // 88
#define CGN   32        // column groups (32 cols each)
#define WGC   32        // cols per WG
#define RWG   8         // row-WGs per group (128 rows each)

static __device__ __forceinline__ unsigned short f2bf(float f){
  unsigned u = __builtin_bit_cast(unsigned, f);
  u += 0x7fffu + ((u >> 16) & 1u);
  return (unsigned short)(u >> 16);
}
static __device__ __forceinline__ float fast_tanh(float x){
  float e = __expf(2.0f * x);          // inf/0 saturate correctly to +/-1
  return 1.0f - 2.0f / (e + 1.0f);
}

// ---- prep: W_ext = [W_res | W_in | 0] in bf16, row-major [1024][1056] ----
// zeros at k>=1032 are LOAD-BEARING: they null garbage in B pad region.
__global__ void k_build_wext(const float* __restrict__ Wres,
                             const float* __restrict__ Win,
                             short* __restrict__ Wext){
  int idx = blockIdx.x * 256 + threadIdx.x;       // 1024*1056 = 4224*256
  int r = idx / KE, k = idx % KE;
  float v = 0.0f;
  if (k < 1024)      v = Wres[(size_t)r * 1024 + k];
  else if (k < 1032) v = Win[r * 8 + (k - 1024)];
  Wext[idx] = (short)f2bf(v);
}

// ---- prep: zero S0+S1 (contiguous 2 x 2,162,688 B) ----
__global__ void k_zero(unsigned* __restrict__ p){
  p[blockIdx.x * 256 + threadIdx.x] = 0u;
}

// ---- prep: x-slot of S0 for step 0, zero flags ----
__global__ void k_init_x(const float* __restrict__ in, short* __restrict__ S0,
                         unsigned* __restrict__ cnt){
  int c = blockIdx.x * 256 + threadIdx.x;
  if (c < 512) cnt[c] = 0u;                 // 32 groups x 8 flags (16-dword stride/group)
  if (c < 1024){
    int t0 = c * LCH - WARM;
    uint4 xv = {0,0,0,0};
    if (t0 >= 0){
      const float4 A4 = *(const float4*)(in + (size_t)t0 * 8);
      const float4 B4 = *(const float4*)(in + (size_t)t0 * 8 + 4);
      xv.x = f2bf(A4.x) | ((unsigned)f2bf(A4.y) << 16);
      xv.y = f2bf(A4.z) | ((unsigned)f2bf(A4.w) << 16);
      xv.z = f2bf(B4.x) | ((unsigned)f2bf(B4.y) << 16);
      xv.w = f2bf(B4.z) | ((unsigned)f2bf(B4.w) << 16);
    }
    *(uint4*)(S0 + (size_t)c * KE + 1024) = xv;
  }
}

// ---- output rows 1024..1031 = inputs^T (exact fp32 copy) ----
__global__ void k_xrows(const float* __restrict__ in, float* __restrict__ out){
  int t = blockIdx.x * 256 + threadIdx.x;
  const float4 a = *(const float4*)(in + (size_t)t * 8);
  const float4 b = *(const float4*)(in + (size_t)t * 8 + 4);
  out[(size_t)(R_DIM + 0) * T_LEN + t] = a.x;
  out[(size_t)(R_DIM + 1) * T_LEN + t] = a.y;
  out[(size_t)(R_DIM + 2) * T_LEN + t] = a.z;
  out[(size_t)(R_DIM + 3) * T_LEN + t] = a.w;
  out[(size_t)(R_DIM + 4) * T_LEN + t] = b.x;
  out[(size_t)(R_DIM + 5) * T_LEN + t] = b.y;
  out[(size_t)(R_DIM + 6) * T_LEN + t] = b.z;
  out[(size_t)(R_DIM + 7) * T_LEN + t] = b.w;
}

// ---- hist[t][r] (bf16) -> out[r][t] (f32), tiled transpose ----
__global__ void k_transpose(const short* __restrict__ hist, float* __restrict__ out){
  __shared__ float tile[64][65];
  const int t0 = blockIdx.x * 64;
  const int r0 = blockIdx.y * 64;
  for (int it = 0; it < 2; ++it){
    int id = it * 256 + threadIdx.x;     // 512 chunks of 8 bf16
    int tr = id >> 3;
    int c8 = (id & 7) * 8;
    short8 v = *(const short8*)(hist + (size_t)(t0 + tr) * KE + r0 + c8);
    #pragma unroll
    for (int j = 0; j < 8; ++j){
      unsigned u = ((unsigned)(unsigned short)v[j]) << 16;
      tile[tr][c8 + j] = __builtin_bit_cast(float, u);
    }
  }
  __syncthreads();
  #pragma unroll
  for (int p = 0; p < 16; ++p){
    int rr = (threadIdx.x >> 6) + p * 4;
    int tc = threadIdx.x & 63;
    out[(size_t)(r0 + rr) * T_LEN + t0 + tc] = tile[tc][rr];
  }
}

// ---- main stepped kernel: 256 WGs x 512 thr; WG = 128 rows x 32 cols ----
// A (weights) live in VGPRs, K split across wave pairs.
// ALL cross-WG data moves via sc0/sc1 (coherence-point) accesses; sync is
// fence-free: producer drains vmcnt(0) then stores a per-WG flag; consumer
// polls the 8 flags (one 64B line) with sc0/sc1 loads. No atomics, no
// buffer_wbl2 / buffer_inv in the loop.
template<bool HIST>
__global__ __launch_bounds__(512, 1)
void k_esn(const float* __restrict__ inputs, const short* __restrict__ Wext,
           short* __restrict__ S0, short* __restrict__ S1,
           short* __restrict__ hist, unsigned* __restrict__ cnt,
           float* __restrict__ out)
{
  __shared__ __align__(16) char lds[65536];   // 32 cols x 2048B (k<1024), XOR-swizzled
  const int tid  = threadIdx.x;
  const int cg   = blockIdx.x & (CGN - 1);
  const int rwg  = blockIdx.x >> 5;           // group WGs: bid = rwg*32+cg -> same XCD
  const int wv   = tid >> 6;                  // 0..7
  const int lane = tid & 63;
  const int l15  = lane & 15, l4 = lane >> 4;
  const int hi   = wv & 1;                    // K-half of this wave
  const int rbase = rwg * 128 + (wv >> 1) * 32;
  const int colbase = cg * WGC;
  unsigned* gflags = cnt + cg * 16;           // 8 dword flags in one 64B line

  auto browf = [&](int col, int k) -> const short* {
    if (!HIST || k <= WARM) return ((k & 1) ? S1 : S0) + (size_t)col * KE;
    return hist + (size_t)(col * LCH + (k - WARM) - 1) * KE;
  };
  auto wrowf = [&](int col, int k) -> short* {
    if (!HIST || (k + 1) <= WARM) return ((k & 1) ? S0 : S1) + (size_t)col * KE;
    return hist + (size_t)(col * LCH + (k - WARM)) * KE;
  };

  // ---- loop-invariant A fragments in registers ----
  // hi=0: kk 0..16 (17 frags); hi=1: kk 17..32 (16 frags; kk32 = global-B tail)
  const int NA = hi ? 16 : 17;
  const int KB = hi ? 17 : 0;
  const int NL = hi ? 15 : 17;   // frags consumed from LDS
  short8 a0[17], a1[17];
  {
    const short* abase = Wext + (size_t)(rbase + l15) * KE + l4 * 8;
    #pragma unroll
    for (int i = 0; i < 17; ++i){
      if (i < NA){
        const short* ap = abase + (KB + i) * 32;
        a0[i] = *(const short8*)ap;
        a1[i] = *(const short8*)(ap + (size_t)16 * KE);
      }
    }
  }

  // staging geometry: thread owns col (tid>>4), 8 chunks of 16B spaced 256B
  const int scol = tid >> 4;
  const int skb0 = (tid & 15) << 4;
  const int sswz = (scol & 7) << 4;
  // B-frag read geometry
  const int colb0 = l15 * 2048;
  const int bswz  = (l15 & 7) << 4;
  const int l4b   = l4 * 16;

  for (int k = 0; k < STEPS; ++k){
    // ---- wait for all 8 producers of this group (fence-free flag poll) ----
    if (k > 0){
      if (wv == 0){
        const unsigned* fp = gflags + (lane & 7);
        int guard = 0;
        for (;;){
          unsigned v;
          asm volatile("global_load_dword %0, %1, off sc0 sc1\n\t"
                       "s_waitcnt vmcnt(0)"
                       : "=v"(v) : "v"(fp) : "memory");
          if (!__any((int)(v < (unsigned)k))) break;
          __builtin_amdgcn_s_sleep(1);
          if (++guard > 1000000) break;      // failsafe: degrade, don't hang
        }
      }
      __syncthreads();                        // A
    }

    // ---- K-ext tail B loads first (latency overlaps staging) ----
    unsigned long long t00=0, t01=0, t10=0, t11=0;
    if (hi){
      const unsigned long long* tp0 =
        (const unsigned long long*)(browf(colbase + l15, k) + 1024 + l4 * 8);
      const unsigned long long* tp1 =
        (const unsigned long long*)(browf(colbase + 16 + l15, k) + 1024 + l4 * 8);
      t00 = __hip_atomic_load(tp0,     __ATOMIC_RELAXED, __HIP_MEMORY_SCOPE_AGENT);
      t01 = __hip_atomic_load(tp0 + 1, __ATOMIC_RELAXED, __HIP_MEMORY_SCOPE_AGENT);
      t10 = __hip_atomic_load(tp1,     __ATOMIC_RELAXED, __HIP_MEMORY_SCOPE_AGENT);
      t11 = __hip_atomic_load(tp1 + 1, __ATOMIC_RELAXED, __HIP_MEMORY_SCOPE_AGENT);
    }

    // ---- stage B (k<1024) into LDS; sc0/sc1 = read at coherence point ----
    {
      const short* srow = browf(colbase + scol, k);
      const char* sp = (const char*)srow + skb0;
      u32x4 r0,r1,r2,r3,r4,r5,r6,r7;
      asm volatile(
        "global_load_dwordx4 %0, %8, off sc0 sc1\n\t"
        "global_load_dwordx4 %1, %8, off offset:256 sc0 sc1\n\t"
        "global_load_dwordx4 %2, %8, off offset:512 sc0 sc1\n\t"
        "global_load_dwordx4 %3, %8, off offset:768 sc0 sc1\n\t"
        "global_load_dwordx4 %4, %8, off offset:1024 sc0 sc1\n\t"
        "global_load_dwordx4 %5, %8, off offset:1280 sc0 sc1\n\t"
        "global_load_dwordx4 %6, %8, off offset:1536 sc0 sc1\n\t"
        "global_load_dwordx4 %7, %8, off offset:1792 sc0 sc1\n\t"
        "s_waitcnt vmcnt(0)"
        : "=&v"(r0),"=&v"(r1),"=&v"(r2),"=&v"(r3),
          "=&v"(r4),"=&v"(r5),"=&v"(r6),"=&v"(r7)
        : "v"(sp) : "memory");
      char* dst = &lds[scol * 2048];
      *(u32x4*)(dst + ((skb0 +    0) ^ sswz)) = r0;
      *(u32x4*)(dst + ((skb0 +  256) ^ sswz)) = r1;
      *(u32x4*)(dst + ((skb0 +  512) ^ sswz)) = r2;
      *(u32x4*)(dst + ((skb0 +  768) ^ sswz)) = r3;
      *(u32x4*)(dst + ((skb0 + 1024) ^ sswz)) = r4;
      *(u32x4*)(dst + ((skb0 + 1280) ^ sswz)) = r5;
      *(u32x4*)(dst + ((skb0 + 1536) ^ sswz)) = r6;
      *(u32x4*)(dst + ((skb0 + 1792) ^ sswz)) = r7;
    }
    __syncthreads();                          // B

    // ---- MFMA K-loop (A from regs, B from LDS) ----
    f32x4 acc00 = {0,0,0,0}, acc01 = {0,0,0,0}, acc10 = {0,0,0,0}, acc11 = {0,0,0,0};
    #pragma unroll
    for (int i = 0; i < 17; ++i){
      if (i < NL){
        int kb = (KB + i) * 64 + l4b;
        const short8 b0 = *(const short8*)(&lds[colb0 + ((kb) ^ bswz)]);
        const short8 b1 = *(const short8*)(&lds[colb0 + 32768 + ((kb) ^ bswz)]);
        acc00 = __builtin_amdgcn_mfma_f32_16x16x32_bf16(a0[i], b0, acc00, 0, 0, 0);
        acc01 = __builtin_amdgcn_mfma_f32_16x16x32_bf16(a0[i], b1, acc01, 0, 0, 0);
        acc10 = __builtin_amdgcn_mfma_f32_16x16x32_bf16(a1[i], b0, acc10, 0, 0, 0);
        acc11 = __builtin_amdgcn_mfma_f32_16x16x32_bf16(a1[i], b1, acc11, 0, 0, 0);
      }
    }
    if (hi){   // kk=32 tail: A index 15, B from registers (pad nulled by Wext zeros)
      u32x4 v0; v0.x=(unsigned)t00; v0.y=(unsigned)(t00>>32); v0.z=(unsigned)t01; v0.w=(unsigned)(t01>>32);
      u32x4 v1; v1.x=(unsigned)t10; v1.y=(unsigned)(t10>>32); v1.z=(unsigned)t11; v1.w=(unsigned)(t11>>32);
      const short8 b0 = __builtin_bit_cast(short8, v0);
      const short8 b1 = __builtin_bit_cast(short8, v1);
      acc00 = __builtin_amdgcn_mfma_f32_16x16x32_bf16(a0[15], b0, acc00, 0, 0, 0);
      acc01 = __builtin_amdgcn_mfma_f32_16x16x32_bf16(a0[15], b1, acc01, 0, 0, 0);
      acc10 = __builtin_amdgcn_mfma_f32_16x16x32_bf16(a1[15], b0, acc10, 0, 0, 0);
      acc11 = __builtin_amdgcn_mfma_f32_16x16x32_bf16(a1[15], b1, acc11, 0, 0, 0);
    }

    // ---- cross-pair K-reduction via LDS (reuse B region after barrier) ----
    __syncthreads();                          // C
    {
      f32x4 wA = hi ? acc00 : acc10;          // this wave's OTHER row-tile partials
      f32x4 wB = hi ? acc01 : acc11;
      char* xp = &lds[wv * 2048 + lane * 32];
      *(f32x4*)(xp)      = wA;
      *(f32x4*)(xp + 16) = wB;
    }
    __syncthreads();                          // D
    {
      const char* pp = &lds[(wv ^ 1) * 2048 + lane * 32];
      f32x4 p0 = *(const f32x4*)(pp);
      f32x4 p1 = *(const f32x4*)(pp + 16);
      f32x4 f0 = (hi ? acc10 : acc00) + p0;   // own row-tile + partner's partial
      f32x4 f1 = (hi ? acc11 : acc01) + p1;
      const int rowb = rbase + hi * 16 + l4 * 4;
      #pragma unroll
      for (int ct = 0; ct < 2; ++ct){
        f32x4 z = ct ? f1 : f0;
        float s0 = fast_tanh(z[0]), s1 = fast_tanh(z[1]);
        float s2 = fast_tanh(z[2]), s3 = fast_tanh(z[3]);
        unsigned long long pk = (unsigned long long)f2bf(s0)
          | ((unsigned long long)f2bf(s1) << 16)
          | ((unsigned long long)f2bf(s2) << 32)
          | ((unsigned long long)f2bf(s3) << 48);
        int col = colbase + ct * 16 + l15;
        short* wp = wrowf(col, k) + rowb;
        asm volatile("global_store_dwordx2 %0, %1, off sc0 sc1"
                     :: "v"(wp), "v"(pk) : "memory");
        if (!HIST && k >= WARM){
          int tk = col * LCH + k - WARM;
          float* op = out + (size_t)rowb * T_LEN + tk;
          op[0] = s0; op[(size_t)T_LEN] = s1;
          op[(size_t)2 * T_LEN] = s2; op[(size_t)3 * T_LEN] = s3;
        }
      }
    }

    // ---- x for next step (one WG per group) ----
    if (rwg == 0 && tid < WGC && (k + 1) < STEPS){
      int col = colbase + tid;
      short* xr = wrowf(col, k) + 1024;
      int tn = col * LCH + (k + 1) - WARM;
      u32x4 xv = {0,0,0,0};
      if (tn >= 0){
        const float4 A4 = *(const float4*)(inputs + (size_t)tn * 8);
        const float4 B4 = *(const float4*)(inputs + (size_t)tn * 8 + 4);
        xv.x = f2bf(A4.x) | ((unsigned)f2bf(A4.y) << 16);
        xv.y = f2bf(A4.z) | ((unsigned)f2bf(A4.w) << 16);
        xv.z = f2bf(B4.x) | ((unsigned)f2bf(B4.y) << 16);
        xv.w = f2bf(B4.z) | ((unsigned)f2bf(B4.w) << 16);
      }
      asm volatile("global_store_dwordx4 %0, %1, off sc0 sc1"
                   :: "v"(xr), "v"(xv) : "memory");
    }

    // ---- drain own stores to coherence point, then signal via flag ----
    asm volatile("s_waitcnt vmcnt(0)" ::: "memory");
    __syncthreads();                          // E (all waves drained)
    if (tid == 0 && (k + 1) < STEPS){
      unsigned* fw = gflags + rwg;
      unsigned fv = (unsigned)(k + 1);
      asm volatile("global_store_dword %0, %1, off sc0 sc1"
                   :: "v"(fw), "v"(fv) : "memory");
    }
  }
}

extern "C" void kernel_launch(void* const* d_in, const int* in_sizes, int n_in,
                              void* d_out, int out_size, void* d_ws, size_t ws_size,
                              hipStream_t stream)
{
  (void)in_sizes; (void)n_in; (void)out_size;
  const float* inputs = (const float*)d_in[0];
  const float* Win    = (const float*)d_in[1];
  const float* Wres   = (const float*)d_in[2];
  float* out = (float*)d_out;
  char* ws = (char*)d_ws;

  short*    Wext = (short*)(ws);                       // 2,162,688 B
  short*    S0   = (short*)(ws + 2162688);             // 2,162,688 B
  short*    S1   = (short*)(ws + 2162688 * 2);         // 2,162,688 B
  unsigned* cnt  = (unsigned*)(ws + 2162688 * 3);      // 32 groups x 8 flags (64B/group)
  short*    hist = (short*)(ws + 6490112);             // 65536*1056*2 = 138,412,032 B
  const bool hist_ok = ws_size >= (6490112ull + 138412032ull);

  hipLaunchKernelGGL(k_build_wext, dim3(4224), dim3(256), 0, stream, Wres, Win, Wext);
  hipLaunchKernelGGL(k_zero,       dim3(4224), dim3(256), 0, stream, (unsigned*)S0);
  hipLaunchKernelGGL(k_init_x,     dim3(4),    dim3(256), 0, stream, inputs, S0, cnt);
  hipLaunchKernelGGL(k_xrows,      dim3(256),  dim3(256), 0, stream, inputs, out);
  if (hist_ok){
    hipLaunchKernelGGL((k_esn<true>),  dim3(RWG * CGN), dim3(512), 0, stream,
                       inputs, Wext, S0, S1, hist, cnt, out);
    hipLaunchKernelGGL(k_transpose, dim3(1024, 16), dim3(256), 0, stream, hist, out);
  } else {
    hipLaunchKernelGGL((k_esn<false>), dim3(RWG * CGN), dim3(512), 0, stream,
                       inputs, Wext, S0, S1, hist, cnt, out);
  }
}